// Round 16
// baseline (183.001 us; speedup 1.0000x reference)
//
#include <hip/hip_runtime.h>

// LeNet forward, BATCH=4096. trunc = zero low 13 bits of fp32 mantissa.
// conv1 FUSED into conv2 (conv1's VALU hides under conv2's MFMA/mem stalls;
// kills the 28MB p1h HBM round-trip). conv2 & fc1 via fp16 hi/lo MFMA.
// conv2: K = 25 pix x 24 icpad = 600 (19 steps); one A-read feeds hi+lo.
// ws layout (bytes):
//   p2h  [4096][800]   fp16 @ 0            ( 6,553,600)
//   h1h  [4096][512]   fp16 @  6,553,600   ( 4,194,304)
//   wph  [19][64][32]  fp16 @ 10,747,904   (    77,824)
//   wpl  [19][64][32]  fp16 @ 10,825,728   (    77,824)
//   wpf1 [25][512][64] fp16 @ 10,903,552   ( 1,638,400)

typedef _Float16 v8h __attribute__((ext_vector_type(8)));
typedef float v4f __attribute__((ext_vector_type(4)));

__device__ __forceinline__ float trunc13(float v) {
    return __int_as_float(__float_as_int(v) & (int)0xFFFFE000u);
}

// ---------------------------------------------------------------------------
// K0a: conv2 weights, hi and lo planes: wp*[t][oc][s] for k=t*32+s:
// pix=k/24, icr=k%24; valid iff k<600 && icr<20 && oc<50.
// ---------------------------------------------------------------------------
__global__ void k_wprep(const float* __restrict__ w2,
                        _Float16* __restrict__ wph, _Float16* __restrict__ wpl) {
    int id = blockIdx.x * 256 + threadIdx.x;
    if (id >= 1216) return;               // 19*64
    int t = id >> 6, oc = id & 63;
    _Float16* dh = wph + (size_t)id * 32;
    _Float16* dl = wpl + (size_t)id * 32;
    for (int s = 0; s < 32; ++s) {
        int k = t * 32 + s;
        int pix = (k * 2731) >> 16;       // /24, exact for k<=600
        int icr = k - pix * 24;
        float w = 0.f;
        if (k < 600 && icr < 20 && oc < 50)
            w = w2[oc * 500 + icr * 25 + pix];
        _Float16 hi = (_Float16)w;
        dh[s] = hi;
        dl[s] = (_Float16)(w - (float)hi);
    }
}

// ---------------------------------------------------------------------------
// K0b: fc1 weight prep: wp1[t][oc][kk]=hi(W[oc][t*32+kk]), [32+kk]=lo
// ---------------------------------------------------------------------------
__global__ void k_w1prep(const float* __restrict__ W, _Float16* __restrict__ Bp) {
    int id = blockIdx.x * 256 + threadIdx.x;   // 25*512 = 12800
    if (id >= 12800) return;
    int t = id >> 9, oc = id & 511;
    _Float16* dst = Bp + (size_t)id * 64;
    for (int kk = 0; kk < 32; ++kk) {
        float w = (oc < 500) ? W[(size_t)oc * 800 + t * 32 + kk] : 0.f;
        _Float16 hi = (_Float16)w;
        _Float16 lo = (_Float16)(w - (float)hi);
        dst[kk] = hi;
        dst[32 + kk] = lo;
    }
}

// ---------------------------------------------------------------------------
// K12: FUSED conv1 (fp32 VALU) + conv2 (fp16 hi/lo MFMA) + both pools.
// Block = 4 images, 256 thr. Phase A: conv1 per (img,pos) writes hv[24]
// directly into LDS Al ([156][24] per image, rows 144+ zeroed). Phase B:
// R15's conv2 K-loop (19 steps; 4 ds_read + 8 L2 B-reads + 32 MFMA) +
// pool epilogue. conv1's VALU hides under conv2's memory stalls (m114).
// ---------------------------------------------------------------------------
#define AIMG3 3744   // 156 rows * 24 halfs
__global__ __launch_bounds__(256) void k_conv12(const float* __restrict__ x,
                                                const float* __restrict__ w1,
                                                const float* __restrict__ b1,
                                                const _Float16* __restrict__ wph,
                                                const _Float16* __restrict__ wpl,
                                                const float* __restrict__ b2,
                                                _Float16* __restrict__ p2h) {
    __shared__ __align__(16) _Float16 Al[4 * AIMG3];   // 29952 B
    __shared__ float wsm[500];
    __shared__ float bsm[20];
    int tid = threadIdx.x;
    int b0 = blockIdx.x * 4;

    for (int t = tid; t < 500; t += 256) wsm[t] = w1[t];
    if (tid < 20) bsm[tid] = b1[tid];
    __syncthreads();

    // ---- Phase A: conv1 into LDS (576 compute tasks + 48 pad-row tasks) ----
    for (int i = tid; i < 624; i += 256) {
        if (i < 576) {
            int img = i / 144, pos = i - img * 144;
            int py = pos / 12, px = pos % 12;
            const float* imgp = x + (size_t)(b0 + img) * 784;

            float patch[36];
#pragma unroll
            for (int r = 0; r < 6; ++r)
#pragma unroll
                for (int c = 0; c < 6; ++c)
                    patch[r * 6 + c] = imgp[(2 * py + r) * 28 + 2 * px + c];

            __align__(16) _Float16 hv[24];
#pragma unroll
            for (int q = 20; q < 24; ++q) hv[q] = (_Float16)0.f;

            for (int oc = 0; oc < 20; ++oc) {
                float bias = bsm[oc];
                float s00 = bias, s01 = bias, s10 = bias, s11 = bias;
                const float* w = &wsm[oc * 25];
#pragma unroll
                for (int ky = 0; ky < 5; ++ky)
#pragma unroll
                    for (int kx = 0; kx < 5; ++kx) {
                        float wv = w[ky * 5 + kx];
                        s00 += patch[ky * 6 + kx] * wv;
                        s01 += patch[ky * 6 + kx + 1] * wv;
                        s10 += patch[(ky + 1) * 6 + kx] * wv;
                        s11 += patch[(ky + 1) * 6 + kx + 1] * wv;
                    }
                float m = fmaxf(fmaxf(fmaxf(trunc13(s00), 0.f), fmaxf(trunc13(s01), 0.f)),
                                fmaxf(fmaxf(trunc13(s10), 0.f), fmaxf(trunc13(s11), 0.f)));
                hv[oc] = (_Float16)m;
            }
            uint4* dst = (uint4*)(Al + img * AIMG3 + pos * 24);
            const uint4* src = (const uint4*)hv;
            dst[0] = src[0]; dst[1] = src[1]; dst[2] = src[2];
        } else {
            int idx = i - 576;               // 48 pad rows: 4 img x rows 144..155
            int img = idx / 12, row = 144 + idx % 12;
            uint4 z = make_uint4(0u, 0u, 0u, 0u);
            uint4* dst = (uint4*)(Al + img * AIMG3 + row * 24);
            dst[0] = z; dst[1] = z; dst[2] = z;
        }
    }
    __syncthreads();

    // ---- Phase B: conv2 MFMA K-loop (R15 verbatim) ----
    int wid = tid >> 6, lane = tid & 63;
    int kg = lane >> 4, rr = lane & 15;
    int Y = rr >> 3, xx = rr & 7;
    const _Float16* Ab = Al + wid * AIMG3;
    const _Float16* abase[4];
#pragma unroll
    for (int my = 0; my < 4; ++my)
        abase[my] = Ab + ((2 * my + Y) * 12 + xx) * 24;
    const _Float16* bh_base = wph + rr * 32 + kg * 8;
    const _Float16* bl_base = wpl + rr * 32 + kg * 8;

    v4f acc[4][4];
#pragma unroll
    for (int my = 0; my < 4; ++my)
#pragma unroll
        for (int nt = 0; nt < 4; ++nt) acc[my][nt] = (v4f){0.f, 0.f, 0.f, 0.f};

    for (int t = 0; t < 19; ++t) {
        int k0 = t * 32 + kg * 8;
        int pix = (k0 * 2731) >> 16;     // /24 exact for k0<=600
        int icol = k0 - pix * 24;
        int ky = (pix * 205) >> 10;      // /5, pix<=25
        int kx = pix - 5 * ky;
        int aofs = (ky * 12 + kx) * 24 + icol;
        v8h af[4];
#pragma unroll
        for (int my = 0; my < 4; ++my)
            af[my] = *(const v8h*)(abase[my] + aofs);
        v8h bv[4];
#pragma unroll
        for (int nt = 0; nt < 4; ++nt)
            bv[nt] = *(const v8h*)(bh_base + t * 2048 + nt * 512);
#pragma unroll
        for (int my = 0; my < 4; ++my)
#pragma unroll
            for (int nt = 0; nt < 4; ++nt)
                acc[my][nt] = __builtin_amdgcn_mfma_f32_16x16x32_f16(af[my], bv[nt], acc[my][nt], 0, 0, 0);
#pragma unroll
        for (int nt = 0; nt < 4; ++nt)
            bv[nt] = *(const v8h*)(bl_base + t * 2048 + nt * 512);
#pragma unroll
        for (int my = 0; my < 4; ++my)
#pragma unroll
            for (int nt = 0; nt < 4; ++nt)
                acc[my][nt] = __builtin_amdgcn_mfma_f32_16x16x32_f16(af[my], bv[nt], acc[my][nt], 0, 0, 0);
    }

    // epilogue: bias + trunc + relu, 2x2 pool (lane-local + xor32) -> fp16
    int imgg = b0 + wid;
#pragma unroll
    for (int nt = 0; nt < 4; ++nt) {
        int oc = nt * 16 + rr;
        float bias = (oc < 50) ? b2[oc] : 0.f;
#pragma unroll
        for (int my = 0; my < 4; ++my) {
            float z0 = fmaxf(trunc13(acc[my][nt][0] + bias), 0.f);
            float z1 = fmaxf(trunc13(acc[my][nt][1] + bias), 0.f);
            float z2 = fmaxf(trunc13(acc[my][nt][2] + bias), 0.f);
            float z3 = fmaxf(trunc13(acc[my][nt][3] + bias), 0.f);
            float s0 = fmaxf(z0, z1), s2 = fmaxf(z2, z3);
            float o0 = fmaxf(s0, __shfl_xor(s0, 32, 64));
            float o2 = fmaxf(s2, __shfl_xor(s2, 32, 64));
            if (kg < 2 && oc < 50) {
                p2h[(size_t)imgg * 800 + oc * 16 + my * 4 + 2 * kg]     = (_Float16)o0;
                p2h[(size_t)imgg * 800 + oc * 16 + my * 4 + 2 * kg + 1] = (_Float16)o2;
            }
        }
    }
}

// ---------------------------------------------------------------------------
// K3: fc1 via MFMA 16x16x32_f16, hi/lo split.  A:[4096,800]fp16 -> H fp16.
// BM=128 BN=64 BK=32, grid 32x8, 4 waves; XOR-swizzled LDS; T14 dbuf.
// ---------------------------------------------------------------------------
__global__ __launch_bounds__(256) void k_fc1(const _Float16* __restrict__ Ah,
                                             const _Float16* __restrict__ Bp,
                                             const float* __restrict__ bias,
                                             _Float16* __restrict__ Hh) {
    __shared__ _Float16 Al[2][4096];
    __shared__ _Float16 Bl[2][4096];
    int tid = threadIdx.x;
    int i0 = blockIdx.x * 128, n0 = blockIdx.y * 64;
    int wid = tid >> 6, lane = tid & 63;
    int rr = lane & 15, kg = lane >> 4;

    int ca0 = tid, ca1 = tid + 256;
    int ra0_ = ca0 >> 2, qa0 = ca0 & 3, ra1_ = ca1 >> 2, qa1 = ca1 & 3;
    int cb0 = tid, cb1 = tid + 256;
    int rb0_ = cb0 >> 3, qb0 = cb0 & 7, rb1_ = cb1 >> 3, qb1 = cb1 & 7;
    int aw0 = (ra0_ * 4 + (qa0 ^ ((ra0_ >> 1) & 3))) * 8;
    int aw1 = (ra1_ * 4 + (qa1 ^ ((ra1_ >> 1) & 3))) * 8;
    int bw0 = (rb0_ * 8 + (qb0 ^ (rb0_ & 7))) * 8;
    int bw1 = (rb1_ * 8 + (qb1 ^ (rb1_ & 7))) * 8;

    uint4 xa0, xa1, xb0, xb1;
    auto loadT = [&](int t) {
        xa0 = *(const uint4*)(Ah + (size_t)(i0 + ra0_) * 800 + t * 32 + qa0 * 8);
        xa1 = *(const uint4*)(Ah + (size_t)(i0 + ra1_) * 800 + t * 32 + qa1 * 8);
        const uint4* g = (const uint4*)(Bp + ((size_t)t * 512 + n0) * 64);
        xb0 = g[cb0]; xb1 = g[cb1];
    };
    auto writeT = [&](int buf) {
        *(uint4*)(&Al[buf][aw0]) = xa0;
        *(uint4*)(&Al[buf][aw1]) = xa1;
        *(uint4*)(&Bl[buf][bw0]) = xb0;
        *(uint4*)(&Bl[buf][bw1]) = xb1;
    };

    int aoff[2], bhoff[4], bloff[4];
#pragma unroll
    for (int mf = 0; mf < 2; ++mf) {
        int r = wid * 32 + mf * 16 + rr;
        aoff[mf] = (r * 4 + (kg ^ ((rr >> 1) & 3))) * 8;
    }
#pragma unroll
    for (int nf = 0; nf < 4; ++nf) {
        int r = nf * 16 + rr;
        bhoff[nf] = (r * 8 + (kg ^ (rr & 7))) * 8;
        bloff[nf] = (r * 8 + ((kg + 4) ^ (rr & 7))) * 8;
    }

    v4f zero = {0.f, 0.f, 0.f, 0.f};
    v4f acc[2][4];
#pragma unroll
    for (int mf = 0; mf < 2; ++mf)
#pragma unroll
        for (int nf = 0; nf < 4; ++nf) acc[mf][nf] = zero;

    loadT(0);
    writeT(0);
    __syncthreads();

    for (int t = 0; t < 25; ++t) {
        int cur = t & 1;
        if (t < 24) loadT(t + 1);
        v8h af[2], bh[4], bl[4];
#pragma unroll
        for (int mf = 0; mf < 2; ++mf) af[mf] = *(const v8h*)(&Al[cur][aoff[mf]]);
#pragma unroll
        for (int nf = 0; nf < 4; ++nf) {
            bh[nf] = *(const v8h*)(&Bl[cur][bhoff[nf]]);
            bl[nf] = *(const v8h*)(&Bl[cur][bloff[nf]]);
        }
#pragma unroll
        for (int mf = 0; mf < 2; ++mf)
#pragma unroll
            for (int nf = 0; nf < 4; ++nf) {
                acc[mf][nf] = __builtin_amdgcn_mfma_f32_16x16x32_f16(af[mf], bh[nf], acc[mf][nf], 0, 0, 0);
                acc[mf][nf] = __builtin_amdgcn_mfma_f32_16x16x32_f16(af[mf], bl[nf], acc[mf][nf], 0, 0, 0);
            }
        if (t < 24) writeT(cur ^ 1);
        __syncthreads();
    }

#pragma unroll
    for (int mf = 0; mf < 2; ++mf)
#pragma unroll
        for (int nf = 0; nf < 4; ++nf) {
            int col = n0 + nf * 16 + rr;
            float bs = bias[col < 500 ? col : 0];
#pragma unroll
            for (int j = 0; j < 4; ++j) {
                int row = i0 + wid * 32 + mf * 16 + kg * 4 + j;
                float v = fmaxf(trunc13(acc[mf][nf][j] + bs), 0.f);
                if (col < 500) Hh[(size_t)row * 512 + col] = (_Float16)v;
            }
        }
}

// ---------------------------------------------------------------------------
// K4: fc2 (500->10) + bias + trunc + log_softmax.  One wave per row, fp16 H.
// ---------------------------------------------------------------------------
__global__ __launch_bounds__(256) void k_fc2(const _Float16* __restrict__ Hh,
                                             const float* __restrict__ W,
                                             const float* __restrict__ bias,
                                             float* __restrict__ out) {
    int wave = threadIdx.x >> 6;
    int lane = threadIdx.x & 63;
    int i = blockIdx.x * 4 + wave;
    const _Float16* hrow = Hh + (size_t)i * 512;

    float p[10];
#pragma unroll
    for (int j = 0; j < 10; ++j) p[j] = 0.f;
    for (int k = lane; k < 500; k += 64) {
        float h = (float)hrow[k];
#pragma unroll
        for (int j = 0; j < 10; ++j) p[j] += h * W[j * 500 + k];
    }
#pragma unroll
    for (int j = 0; j < 10; ++j)
#pragma unroll
        for (int off = 32; off; off >>= 1) p[j] += __shfl_xor(p[j], off, 64);

    if (lane == 0) {
        float z[10], m = -1e30f;
#pragma unroll
        for (int j = 0; j < 10; ++j) {
            z[j] = trunc13(p[j] + bias[j]);
            m = fmaxf(m, z[j]);
        }
        float s = 0.f;
#pragma unroll
        for (int j = 0; j < 10; ++j) s += expf(z[j] - m);
        float lse = m + logf(s);
#pragma unroll
        for (int j = 0; j < 10; ++j) out[(size_t)i * 10 + j] = z[j] - lse;
    }
}

// ---------------------------------------------------------------------------
extern "C" void kernel_launch(void* const* d_in, const int* in_sizes, int n_in,
                              void* d_out, int out_size, void* d_ws, size_t ws_size,
                              hipStream_t stream) {
    const float* x   = (const float*)d_in[0];
    const float* w1  = (const float*)d_in[1];
    const float* b1  = (const float*)d_in[2];
    const float* w2  = (const float*)d_in[3];
    const float* b2  = (const float*)d_in[4];
    const float* wf1 = (const float*)d_in[5];
    const float* bf1 = (const float*)d_in[6];
    const float* wf2 = (const float*)d_in[7];
    const float* bf2 = (const float*)d_in[8];
    float* out = (float*)d_out;

    char* ws = (char*)d_ws;
    _Float16* p2h  = (_Float16*)(ws);                   //  6,553,600
    _Float16* h1h  = (_Float16*)(ws + 6553600);         //  4,194,304
    _Float16* wph  = (_Float16*)(ws + 10747904);        //     77,824
    _Float16* wpl  = (_Float16*)(ws + 10825728);        //     77,824
    _Float16* wpf1 = (_Float16*)(ws + 10903552);        //  1,638,400

    k_wprep<<<5, 256, 0, stream>>>(w2, wph, wpl);
    k_w1prep<<<50, 256, 0, stream>>>(wf1, wpf1);
    k_conv12<<<1024, 256, 0, stream>>>(x, w1, b1, wph, wpl, b2, p2h);
    dim3 g3(32, 8);
    k_fc1<<<g3, 256, 0, stream>>>(p2h, wpf1, bf1, h1h);
    k_fc2<<<1024, 256, 0, stream>>>(h1h, wf2, bf2, out);
}

// Round 17
// 136.348 us; speedup vs baseline: 1.3422x; 1.3422x over previous
//
#include <hip/hip_runtime.h>

// LeNet forward, BATCH=4096. trunc = zero low 13 bits of fp32 mantissa.
// conv2 & fc1 via fp16 hi/lo-split MFMA. conv2: K = 25 pix x 24 icpad = 600
// (19 steps); wave = TWO images (my=8, nt=4): 64-MFMA burst (~310 cyc) >
// L2 latency (~250) so 2 waves/SIMD cover each other -- R10-R15 plateaued
// at 25% MfmaUtil because 16-MFMA bursts (77 cyc) were too short.
// ws layout (bytes):
//   p1h  [4096][144][24] fp16 @ 0            (28,311,552)
//   p2h  [4096][800]     fp16 @ 28,311,552   ( 6,553,600)
//   h1h  [4096][512]     fp16 @ 34,865,152   ( 4,194,304)
//   wph  [19][64][32]    fp16 @ 39,059,456   (    77,824)
//   wpl  [19][64][32]    fp16 @ 39,137,280   (    77,824)
//   wpf1 [25][512][64]   fp16 @ 39,215,104   ( 1,638,400)

typedef _Float16 v8h __attribute__((ext_vector_type(8)));
typedef float v4f __attribute__((ext_vector_type(4)));

__device__ __forceinline__ float trunc13(float v) {
    return __int_as_float(__float_as_int(v) & (int)0xFFFFE000u);
}

// ---------------------------------------------------------------------------
// K0a: conv2 weights, hi and lo planes: wp*[t][oc][s] for k=t*32+s:
// pix=k/24, icr=k%24; valid iff k<600 && icr<20 && oc<50.
// ---------------------------------------------------------------------------
__global__ void k_wprep(const float* __restrict__ w2,
                        _Float16* __restrict__ wph, _Float16* __restrict__ wpl) {
    int id = blockIdx.x * 256 + threadIdx.x;
    if (id >= 1216) return;               // 19*64
    int t = id >> 6, oc = id & 63;
    _Float16* dh = wph + (size_t)id * 32;
    _Float16* dl = wpl + (size_t)id * 32;
    for (int s = 0; s < 32; ++s) {
        int k = t * 32 + s;
        int pix = (k * 2731) >> 16;       // /24, exact for k<=600
        int icr = k - pix * 24;
        float w = 0.f;
        if (k < 600 && icr < 20 && oc < 50)
            w = w2[oc * 500 + icr * 25 + pix];
        _Float16 hi = (_Float16)w;
        dh[s] = hi;
        dl[s] = (_Float16)(w - (float)hi);
    }
}

// ---------------------------------------------------------------------------
// K0b: fc1 weight prep: wp1[t][oc][kk]=hi(W[oc][t*32+kk]), [32+kk]=lo
// ---------------------------------------------------------------------------
__global__ void k_w1prep(const float* __restrict__ W, _Float16* __restrict__ Bp) {
    int id = blockIdx.x * 256 + threadIdx.x;   // 25*512 = 12800
    if (id >= 12800) return;
    int t = id >> 9, oc = id & 511;
    _Float16* dst = Bp + (size_t)id * 64;
    for (int kk = 0; kk < 32; ++kk) {
        float w = (oc < 500) ? W[(size_t)oc * 800 + t * 32 + kk] : 0.f;
        _Float16 hi = (_Float16)w;
        _Float16 lo = (_Float16)(w - (float)hi);
        dst[kk] = hi;
        dst[32 + kk] = lo;
    }
}

// ---------------------------------------------------------------------------
// K1: conv1 + bias + trunc + relu + 2x2 maxpool -> fp16 [img][pos][24]
// ---------------------------------------------------------------------------
__global__ __launch_bounds__(256) void k_conv1(const float* __restrict__ x,
                                               const float* __restrict__ w1,
                                               const float* __restrict__ b1,
                                               _Float16* __restrict__ p1h) {
    __shared__ float wsm[500];
    __shared__ float bsm[20];
    int tid = threadIdx.x;
    for (int t = tid; t < 500; t += 256) wsm[t] = w1[t];
    if (tid < 20) bsm[tid] = b1[tid];
    __syncthreads();

    int gid = blockIdx.x * 256 + tid;   // 4096*144 = 2304*256 exact
    int b   = gid / 144;
    int pos = gid % 144;
    int py = pos / 12, px = pos % 12;
    const float* img = x + (size_t)b * 784;

    float patch[36];
#pragma unroll
    for (int r = 0; r < 6; ++r)
#pragma unroll
        for (int c = 0; c < 6; ++c)
            patch[r * 6 + c] = img[(2 * py + r) * 28 + 2 * px + c];

    __align__(16) _Float16 hv[24];
#pragma unroll
    for (int q = 20; q < 24; ++q) hv[q] = (_Float16)0.f;

    for (int oc = 0; oc < 20; ++oc) {
        float bias = bsm[oc];
        float s00 = bias, s01 = bias, s10 = bias, s11 = bias;
        const float* w = &wsm[oc * 25];
#pragma unroll
        for (int ky = 0; ky < 5; ++ky)
#pragma unroll
            for (int kx = 0; kx < 5; ++kx) {
                float wv = w[ky * 5 + kx];
                s00 += patch[ky * 6 + kx] * wv;
                s01 += patch[ky * 6 + kx + 1] * wv;
                s10 += patch[(ky + 1) * 6 + kx] * wv;
                s11 += patch[(ky + 1) * 6 + kx + 1] * wv;
            }
        float m = fmaxf(fmaxf(fmaxf(trunc13(s00), 0.f), fmaxf(trunc13(s01), 0.f)),
                        fmaxf(fmaxf(trunc13(s10), 0.f), fmaxf(trunc13(s11), 0.f)));
        hv[oc] = (_Float16)m;
    }
    uint4* outp = (uint4*)(p1h + ((size_t)b * 144 + pos) * 24);
    const uint4* src = (const uint4*)hv;
    outp[0] = src[0]; outp[1] = src[1]; outp[2] = src[2];
}

// ---------------------------------------------------------------------------
// K2: conv2 via MFMA 16x16x32_f16. Block = 8 images, 4 waves; wave = 2
// images (my=8), nt=4. Per K-step: 8 A ds_read + 8 B L2 reads + 64 MFMA
// (~310 cyc burst). LDS 59.9 KB -> 2 blocks/CU, 2 waves/SIMD; launch_bounds
// (256,2) pins VGPR <= 256 (est ~200, no spill). No K-loop barriers.
// ---------------------------------------------------------------------------
#define AIMG3 3744   // 156 rows * 24 halfs (rows 144..155 zero pad)
__global__ __launch_bounds__(256, 2) void k_conv2(const _Float16* __restrict__ p1h,
                                                  const _Float16* __restrict__ wph,
                                                  const _Float16* __restrict__ wpl,
                                                  const float* __restrict__ b2,
                                                  _Float16* __restrict__ p2h) {
    __shared__ __align__(16) _Float16 Al[8 * AIMG3];   // 59904 B
    int tid = threadIdx.x;
    int b0 = blockIdx.x * 8;

    // stage: per img 432 uint4 copy + 36 uint4 zero pad
    {
        const uint4* src = (const uint4*)(p1h + (size_t)b0 * 3456);
        uint4* dst = (uint4*)Al;
        uint4 z = make_uint4(0u, 0u, 0u, 0u);
        for (int i = tid; i < 3744; i += 256) {
            int img = i / 468, r = i - img * 468;
            dst[i] = (r < 432) ? src[img * 432 + r] : z;
        }
    }
    __syncthreads();

    int wid = tid >> 6, lane = tid & 63;
    int kg = lane >> 4, rr = lane & 15;
    int Y = rr >> 3, xx = rr & 7;
    const _Float16* Ab0 = Al + (wid * 2) * AIMG3;      // image pair
    const _Float16* Ab1 = Ab0 + AIMG3;
    const _Float16* abase[8];
#pragma unroll
    for (int my = 0; my < 4; ++my) {
        abase[my]     = Ab0 + ((2 * my + Y) * 12 + xx) * 24;
        abase[my + 4] = Ab1 + ((2 * my + Y) * 12 + xx) * 24;
    }
    const _Float16* bh_base = wph + rr * 32 + kg * 8;
    const _Float16* bl_base = wpl + rr * 32 + kg * 8;

    v4f acc[8][4];
#pragma unroll
    for (int my = 0; my < 8; ++my)
#pragma unroll
        for (int nt = 0; nt < 4; ++nt) acc[my][nt] = (v4f){0.f, 0.f, 0.f, 0.f};

    for (int t = 0; t < 19; ++t) {
        int k0 = t * 32 + kg * 8;
        int pix = (k0 * 2731) >> 16;     // /24 exact for k0<=600
        int icol = k0 - pix * 24;
        int ky = (pix * 205) >> 10;      // /5, pix<=25
        int kx = pix - 5 * ky;
        int aofs = (ky * 12 + kx) * 24 + icol;
        v8h af[8];
#pragma unroll
        for (int my = 0; my < 8; ++my)
            af[my] = *(const v8h*)(abase[my] + aofs);
        v8h bh[4], bl[4];
#pragma unroll
        for (int nt = 0; nt < 4; ++nt) {
            bh[nt] = *(const v8h*)(bh_base + t * 2048 + nt * 512);
            bl[nt] = *(const v8h*)(bl_base + t * 2048 + nt * 512);
        }
#pragma unroll
        for (int my = 0; my < 8; ++my)
#pragma unroll
            for (int nt = 0; nt < 4; ++nt)
                acc[my][nt] = __builtin_amdgcn_mfma_f32_16x16x32_f16(af[my], bh[nt], acc[my][nt], 0, 0, 0);
#pragma unroll
        for (int my = 0; my < 8; ++my)
#pragma unroll
            for (int nt = 0; nt < 4; ++nt)
                acc[my][nt] = __builtin_amdgcn_mfma_f32_16x16x32_f16(af[my], bl[nt], acc[my][nt], 0, 0, 0);
    }

    // epilogue: bias + trunc + relu, 2x2 pool (lane-local + xor32) -> fp16
#pragma unroll
    for (int h = 0; h < 2; ++h) {
        int imgg = b0 + wid * 2 + h;
#pragma unroll
        for (int nt = 0; nt < 4; ++nt) {
            int oc = nt * 16 + rr;
            float bias = (oc < 50) ? b2[oc] : 0.f;
#pragma unroll
            for (int my = 0; my < 4; ++my) {
                v4f a = acc[h * 4 + my][nt];
                float z0 = fmaxf(trunc13(a[0] + bias), 0.f);
                float z1 = fmaxf(trunc13(a[1] + bias), 0.f);
                float z2 = fmaxf(trunc13(a[2] + bias), 0.f);
                float z3 = fmaxf(trunc13(a[3] + bias), 0.f);
                float s0 = fmaxf(z0, z1), s2 = fmaxf(z2, z3);
                float o0 = fmaxf(s0, __shfl_xor(s0, 32, 64));
                float o2 = fmaxf(s2, __shfl_xor(s2, 32, 64));
                if (kg < 2 && oc < 50) {
                    p2h[(size_t)imgg * 800 + oc * 16 + my * 4 + 2 * kg]     = (_Float16)o0;
                    p2h[(size_t)imgg * 800 + oc * 16 + my * 4 + 2 * kg + 1] = (_Float16)o2;
                }
            }
        }
    }
}

// ---------------------------------------------------------------------------
// K3: fc1 via MFMA 16x16x32_f16, hi/lo split.  A:[4096,800]fp16 -> H fp16.
// BM=128 BN=64 BK=32, grid 32x8, 4 waves; XOR-swizzled LDS; T14 dbuf.
// ---------------------------------------------------------------------------
__global__ __launch_bounds__(256) void k_fc1(const _Float16* __restrict__ Ah,
                                             const _Float16* __restrict__ Bp,
                                             const float* __restrict__ bias,
                                             _Float16* __restrict__ Hh) {
    __shared__ _Float16 Al[2][4096];
    __shared__ _Float16 Bl[2][4096];
    int tid = threadIdx.x;
    int i0 = blockIdx.x * 128, n0 = blockIdx.y * 64;
    int wid = tid >> 6, lane = tid & 63;
    int rr = lane & 15, kg = lane >> 4;

    int ca0 = tid, ca1 = tid + 256;
    int ra0_ = ca0 >> 2, qa0 = ca0 & 3, ra1_ = ca1 >> 2, qa1 = ca1 & 3;
    int cb0 = tid, cb1 = tid + 256;
    int rb0_ = cb0 >> 3, qb0 = cb0 & 7, rb1_ = cb1 >> 3, qb1 = cb1 & 7;
    int aw0 = (ra0_ * 4 + (qa0 ^ ((ra0_ >> 1) & 3))) * 8;
    int aw1 = (ra1_ * 4 + (qa1 ^ ((ra1_ >> 1) & 3))) * 8;
    int bw0 = (rb0_ * 8 + (qb0 ^ (rb0_ & 7))) * 8;
    int bw1 = (rb1_ * 8 + (qb1 ^ (rb1_ & 7))) * 8;

    uint4 xa0, xa1, xb0, xb1;
    auto loadT = [&](int t) {
        xa0 = *(const uint4*)(Ah + (size_t)(i0 + ra0_) * 800 + t * 32 + qa0 * 8);
        xa1 = *(const uint4*)(Ah + (size_t)(i0 + ra1_) * 800 + t * 32 + qa1 * 8);
        const uint4* g = (const uint4*)(Bp + ((size_t)t * 512 + n0) * 64);
        xb0 = g[cb0]; xb1 = g[cb1];
    };
    auto writeT = [&](int buf) {
        *(uint4*)(&Al[buf][aw0]) = xa0;
        *(uint4*)(&Al[buf][aw1]) = xa1;
        *(uint4*)(&Bl[buf][bw0]) = xb0;
        *(uint4*)(&Bl[buf][bw1]) = xb1;
    };

    int aoff[2], bhoff[4], bloff[4];
#pragma unroll
    for (int mf = 0; mf < 2; ++mf) {
        int r = wid * 32 + mf * 16 + rr;
        aoff[mf] = (r * 4 + (kg ^ ((rr >> 1) & 3))) * 8;
    }
#pragma unroll
    for (int nf = 0; nf < 4; ++nf) {
        int r = nf * 16 + rr;
        bhoff[nf] = (r * 8 + (kg ^ (rr & 7))) * 8;
        bloff[nf] = (r * 8 + ((kg + 4) ^ (rr & 7))) * 8;
    }

    v4f zero = {0.f, 0.f, 0.f, 0.f};
    v4f acc[2][4];
#pragma unroll
    for (int mf = 0; mf < 2; ++mf)
#pragma unroll
        for (int nf = 0; nf < 4; ++nf) acc[mf][nf] = zero;

    loadT(0);
    writeT(0);
    __syncthreads();

    for (int t = 0; t < 25; ++t) {
        int cur = t & 1;
        if (t < 24) loadT(t + 1);
        v8h af[2], bh[4], bl[4];
#pragma unroll
        for (int mf = 0; mf < 2; ++mf) af[mf] = *(const v8h*)(&Al[cur][aoff[mf]]);
#pragma unroll
        for (int nf = 0; nf < 4; ++nf) {
            bh[nf] = *(const v8h*)(&Bl[cur][bhoff[nf]]);
            bl[nf] = *(const v8h*)(&Bl[cur][bloff[nf]]);
        }
#pragma unroll
        for (int mf = 0; mf < 2; ++mf)
#pragma unroll
            for (int nf = 0; nf < 4; ++nf) {
                acc[mf][nf] = __builtin_amdgcn_mfma_f32_16x16x32_f16(af[mf], bh[nf], acc[mf][nf], 0, 0, 0);
                acc[mf][nf] = __builtin_amdgcn_mfma_f32_16x16x32_f16(af[mf], bl[nf], acc[mf][nf], 0, 0, 0);
            }
        if (t < 24) writeT(cur ^ 1);
        __syncthreads();
    }

#pragma unroll
    for (int mf = 0; mf < 2; ++mf)
#pragma unroll
        for (int nf = 0; nf < 4; ++nf) {
            int col = n0 + nf * 16 + rr;
            float bs = bias[col < 500 ? col : 0];
#pragma unroll
            for (int j = 0; j < 4; ++j) {
                int row = i0 + wid * 32 + mf * 16 + kg * 4 + j;
                float v = fmaxf(trunc13(acc[mf][nf][j] + bs), 0.f);
                if (col < 500) Hh[(size_t)row * 512 + col] = (_Float16)v;
            }
        }
}

// ---------------------------------------------------------------------------
// K4: fc2 (500->10) + bias + trunc + log_softmax.  One wave per row, fp16 H.
// ---------------------------------------------------------------------------
__global__ __launch_bounds__(256) void k_fc2(const _Float16* __restrict__ Hh,
                                             const float* __restrict__ W,
                                             const float* __restrict__ bias,
                                             float* __restrict__ out) {
    int wave = threadIdx.x >> 6;
    int lane = threadIdx.x & 63;
    int i = blockIdx.x * 4 + wave;
    const _Float16* hrow = Hh + (size_t)i * 512;

    float p[10];
#pragma unroll
    for (int j = 0; j < 10; ++j) p[j] = 0.f;
    for (int k = lane; k < 500; k += 64) {
        float h = (float)hrow[k];
#pragma unroll
        for (int j = 0; j < 10; ++j) p[j] += h * W[j * 500 + k];
    }
#pragma unroll
    for (int j = 0; j < 10; ++j)
#pragma unroll
        for (int off = 32; off; off >>= 1) p[j] += __shfl_xor(p[j], off, 64);

    if (lane == 0) {
        float z[10], m = -1e30f;
#pragma unroll
        for (int j = 0; j < 10; ++j) {
            z[j] = trunc13(p[j] + bias[j]);
            m = fmaxf(m, z[j]);
        }
        float s = 0.f;
#pragma unroll
        for (int j = 0; j < 10; ++j) s += expf(z[j] - m);
        float lse = m + logf(s);
#pragma unroll
        for (int j = 0; j < 10; ++j) out[(size_t)i * 10 + j] = z[j] - lse;
    }
}

// ---------------------------------------------------------------------------
extern "C" void kernel_launch(void* const* d_in, const int* in_sizes, int n_in,
                              void* d_out, int out_size, void* d_ws, size_t ws_size,
                              hipStream_t stream) {
    const float* x   = (const float*)d_in[0];
    const float* w1  = (const float*)d_in[1];
    const float* b1  = (const float*)d_in[2];
    const float* w2  = (const float*)d_in[3];
    const float* b2  = (const float*)d_in[4];
    const float* wf1 = (const float*)d_in[5];
    const float* bf1 = (const float*)d_in[6];
    const float* wf2 = (const float*)d_in[7];
    const float* bf2 = (const float*)d_in[8];
    float* out = (float*)d_out;

    char* ws = (char*)d_ws;
    _Float16* p1h  = (_Float16*)(ws);                   // 28,311,552
    _Float16* p2h  = (_Float16*)(ws + 28311552);        //  6,553,600
    _Float16* h1h  = (_Float16*)(ws + 34865152);        //  4,194,304
    _Float16* wph  = (_Float16*)(ws + 39059456);        //     77,824
    _Float16* wpl  = (_Float16*)(ws + 39137280);        //     77,824
    _Float16* wpf1 = (_Float16*)(ws + 39215104);        //  1,638,400

    k_wprep<<<5, 256, 0, stream>>>(w2, wph, wpl);
    k_w1prep<<<50, 256, 0, stream>>>(wf1, wpf1);
    k_conv1<<<2304, 256, 0, stream>>>(x, w1, b1, p1h);
    k_conv2<<<512, 256, 0, stream>>>(p1h, wph, wpl, b2, p2h);
    dim3 g3(32, 8);
    k_fc1<<<g3, 256, 0, stream>>>(p2h, wpf1, bf1, h1h);
    k_fc2<<<1024, 256, 0, stream>>>(h1h, wf2, bf2, out);
}

// Round 18
// 118.495 us; speedup vs baseline: 1.5444x; 1.1507x over previous
//
#include <hip/hip_runtime.h>

// LeNet forward, BATCH=4096. trunc = zero low 13 bits of fp32 mantissa.
// conv2 & fc1 via fp16 MFMA, HI-PLANE ONLY (fp16 weight rounding err is
// sub-trunc-granule: w~U(+-1/sqrt(fanin)), err ~7e-5 < granule ~1.2e-4).
// conv2: K = 25 pix x 24 icpad, padded to 20 steps of 32; TWO K-steps per
// iteration (B both steps preloaded) keeps the 64-MFMA burst (R17 lever).
// ws layout (bytes):
//   p1h  [4096][144][24] fp16 @ 0            (28,311,552)
//   p2h  [4096][800]     fp16 @ 28,311,552   ( 6,553,600)
//   h1h  [4096][512]     fp16 @ 34,865,152   ( 4,194,304)
//   wph  [20][64][32]    fp16 @ 39,059,456   (    81,920)
//   wpf1 [25][512][64]   fp16 @ 39,141,376   ( 1,638,400)

typedef _Float16 v8h __attribute__((ext_vector_type(8)));
typedef float v4f __attribute__((ext_vector_type(4)));

__device__ __forceinline__ float trunc13(float v) {
    return __int_as_float(__float_as_int(v) & (int)0xFFFFE000u);
}

// ---------------------------------------------------------------------------
// K0a: conv2 hi weights: wph[t][oc][s] for k=t*32+s: pix=k/24, icr=k%24;
// valid iff pix<25 && icr<20 && oc<50, else 0. t<20 (tail zeros).
// ---------------------------------------------------------------------------
__global__ void k_wprep(const float* __restrict__ w2, _Float16* __restrict__ wph) {
    int id = blockIdx.x * 256 + threadIdx.x;
    if (id >= 1280) return;               // 20*64
    int t = id >> 6, oc = id & 63;
    _Float16* dh = wph + (size_t)id * 32;
    for (int s = 0; s < 32; ++s) {
        int k = t * 32 + s;
        int pix = (k * 2731) >> 16;       // /24, exact for k<640
        int icr = k - pix * 24;
        float w = 0.f;
        if (pix < 25 && icr < 20 && oc < 50)
            w = w2[oc * 500 + icr * 25 + pix];
        dh[s] = (_Float16)w;
    }
}

// ---------------------------------------------------------------------------
// K0b: fc1 weight prep: wp1[t][oc][kk]=hi(W[oc][t*32+kk]), [32+kk]=lo
// (lo kept in layout for easy revert; fc1 reads hi half only)
// ---------------------------------------------------------------------------
__global__ void k_w1prep(const float* __restrict__ W, _Float16* __restrict__ Bp) {
    int id = blockIdx.x * 256 + threadIdx.x;   // 25*512 = 12800
    if (id >= 12800) return;
    int t = id >> 9, oc = id & 511;
    _Float16* dst = Bp + (size_t)id * 64;
    for (int kk = 0; kk < 32; ++kk) {
        float w = (oc < 500) ? W[(size_t)oc * 800 + t * 32 + kk] : 0.f;
        _Float16 hi = (_Float16)w;
        _Float16 lo = (_Float16)(w - (float)hi);
        dst[kk] = hi;
        dst[32 + kk] = lo;
    }
}

// ---------------------------------------------------------------------------
// K1: conv1 + bias + trunc + relu + 2x2 maxpool -> fp16 [img][pos][24]
// ---------------------------------------------------------------------------
__global__ __launch_bounds__(256) void k_conv1(const float* __restrict__ x,
                                               const float* __restrict__ w1,
                                               const float* __restrict__ b1,
                                               _Float16* __restrict__ p1h) {
    __shared__ float wsm[500];
    __shared__ float bsm[20];
    int tid = threadIdx.x;
    for (int t = tid; t < 500; t += 256) wsm[t] = w1[t];
    if (tid < 20) bsm[tid] = b1[tid];
    __syncthreads();

    int gid = blockIdx.x * 256 + tid;   // 4096*144 = 2304*256 exact
    int b   = gid / 144;
    int pos = gid % 144;
    int py = pos / 12, px = pos % 12;
    const float* img = x + (size_t)b * 784;

    float patch[36];
#pragma unroll
    for (int r = 0; r < 6; ++r)
#pragma unroll
        for (int c = 0; c < 6; ++c)
            patch[r * 6 + c] = img[(2 * py + r) * 28 + 2 * px + c];

    __align__(16) _Float16 hv[24];
#pragma unroll
    for (int q = 20; q < 24; ++q) hv[q] = (_Float16)0.f;

    for (int oc = 0; oc < 20; ++oc) {
        float bias = bsm[oc];
        float s00 = bias, s01 = bias, s10 = bias, s11 = bias;
        const float* w = &wsm[oc * 25];
#pragma unroll
        for (int ky = 0; ky < 5; ++ky)
#pragma unroll
            for (int kx = 0; kx < 5; ++kx) {
                float wv = w[ky * 5 + kx];
                s00 += patch[ky * 6 + kx] * wv;
                s01 += patch[ky * 6 + kx + 1] * wv;
                s10 += patch[(ky + 1) * 6 + kx] * wv;
                s11 += patch[(ky + 1) * 6 + kx + 1] * wv;
            }
        float m = fmaxf(fmaxf(fmaxf(trunc13(s00), 0.f), fmaxf(trunc13(s01), 0.f)),
                        fmaxf(fmaxf(trunc13(s10), 0.f), fmaxf(trunc13(s11), 0.f)));
        hv[oc] = (_Float16)m;
    }
    uint4* outp = (uint4*)(p1h + ((size_t)b * 144 + pos) * 24);
    const uint4* src = (const uint4*)hv;
    outp[0] = src[0]; outp[1] = src[1]; outp[2] = src[2];
}

// ---------------------------------------------------------------------------
// K2: conv2 via MFMA 16x16x32_f16, hi-only. Block = 8 images, 4 waves;
// wave = 2 images (my=8), nt=4. Iteration = 2 K-steps: B(t0,t1) preloaded,
// A per sub-step -> 64-MFMA burst per 24 loads. 20 K-steps (tail zeros).
// ---------------------------------------------------------------------------
#define AIMG3 3744   // 156 rows * 24 halfs (rows 144..155 zero pad)
__global__ __launch_bounds__(256, 2) void k_conv2(const _Float16* __restrict__ p1h,
                                                  const _Float16* __restrict__ wph,
                                                  const float* __restrict__ b2,
                                                  _Float16* __restrict__ p2h) {
    __shared__ __align__(16) _Float16 Al[8 * AIMG3];   // 59904 B
    int tid = threadIdx.x;
    int b0 = blockIdx.x * 8;

    {
        const uint4* src = (const uint4*)(p1h + (size_t)b0 * 3456);
        uint4* dst = (uint4*)Al;
        uint4 z = make_uint4(0u, 0u, 0u, 0u);
        for (int i = tid; i < 3744; i += 256) {
            int img = i / 468, r = i - img * 468;
            dst[i] = (r < 432) ? src[img * 432 + r] : z;
        }
    }
    __syncthreads();

    int wid = tid >> 6, lane = tid & 63;
    int kg = lane >> 4, rr = lane & 15;
    int Y = rr >> 3, xx = rr & 7;
    const _Float16* Ab0 = Al + (wid * 2) * AIMG3;
    const _Float16* Ab1 = Ab0 + AIMG3;
    const _Float16* abase[8];
#pragma unroll
    for (int my = 0; my < 4; ++my) {
        abase[my]     = Ab0 + ((2 * my + Y) * 12 + xx) * 24;
        abase[my + 4] = Ab1 + ((2 * my + Y) * 12 + xx) * 24;
    }
    const _Float16* bh_base = wph + rr * 32 + kg * 8;

    v4f acc[8][4];
#pragma unroll
    for (int my = 0; my < 8; ++my)
#pragma unroll
        for (int nt = 0; nt < 4; ++nt) acc[my][nt] = (v4f){0.f, 0.f, 0.f, 0.f};

    for (int u = 0; u < 10; ++u) {
        int t0 = 2 * u, t1 = 2 * u + 1;
        v8h bA[4], bB[4];
#pragma unroll
        for (int nt = 0; nt < 4; ++nt) {
            bA[nt] = *(const v8h*)(bh_base + t0 * 2048 + nt * 512);
            bB[nt] = *(const v8h*)(bh_base + t1 * 2048 + nt * 512);
        }
        // ---- sub-step 0 ----
        {
            int k0 = t0 * 32 + kg * 8;
            int pix = (k0 * 2731) >> 16;
            int icol = k0 - pix * 24;
            int ky = (pix * 205) >> 10;
            int kx = pix - 5 * ky;
            int aofs = (ky * 12 + kx) * 24 + icol;
            v8h af[8];
#pragma unroll
            for (int my = 0; my < 8; ++my)
                af[my] = *(const v8h*)(abase[my] + aofs);
#pragma unroll
            for (int my = 0; my < 8; ++my)
#pragma unroll
                for (int nt = 0; nt < 4; ++nt)
                    acc[my][nt] = __builtin_amdgcn_mfma_f32_16x16x32_f16(af[my], bA[nt], acc[my][nt], 0, 0, 0);
        }
        // ---- sub-step 1 ----
        {
            int k0 = t1 * 32 + kg * 8;
            int pix = (k0 * 2731) >> 16;
            int icol = k0 - pix * 24;
            int ky = (pix * 205) >> 10;
            int kx = pix - 5 * ky;
            int aofs = (ky * 12 + kx) * 24 + icol;
            v8h af[8];
#pragma unroll
            for (int my = 0; my < 8; ++my)
                af[my] = *(const v8h*)(abase[my] + aofs);
#pragma unroll
            for (int my = 0; my < 8; ++my)
#pragma unroll
                for (int nt = 0; nt < 4; ++nt)
                    acc[my][nt] = __builtin_amdgcn_mfma_f32_16x16x32_f16(af[my], bB[nt], acc[my][nt], 0, 0, 0);
        }
    }

    // epilogue: bias + trunc + relu, 2x2 pool (lane-local + xor32) -> fp16
#pragma unroll
    for (int h = 0; h < 2; ++h) {
        int imgg = b0 + wid * 2 + h;
#pragma unroll
        for (int nt = 0; nt < 4; ++nt) {
            int oc = nt * 16 + rr;
            float bias = (oc < 50) ? b2[oc] : 0.f;
#pragma unroll
            for (int my = 0; my < 4; ++my) {
                v4f a = acc[h * 4 + my][nt];
                float z0 = fmaxf(trunc13(a[0] + bias), 0.f);
                float z1 = fmaxf(trunc13(a[1] + bias), 0.f);
                float z2 = fmaxf(trunc13(a[2] + bias), 0.f);
                float z3 = fmaxf(trunc13(a[3] + bias), 0.f);
                float s0 = fmaxf(z0, z1), s2 = fmaxf(z2, z3);
                float o0 = fmaxf(s0, __shfl_xor(s0, 32, 64));
                float o2 = fmaxf(s2, __shfl_xor(s2, 32, 64));
                if (kg < 2 && oc < 50) {
                    p2h[(size_t)imgg * 800 + oc * 16 + my * 4 + 2 * kg]     = (_Float16)o0;
                    p2h[(size_t)imgg * 800 + oc * 16 + my * 4 + 2 * kg + 1] = (_Float16)o2;
                }
            }
        }
    }
}

// ---------------------------------------------------------------------------
// K3: fc1 via MFMA 16x16x32_f16, hi-only. BM=128 BN=64 BK=32, grid 32x8,
// 4 waves; A XOR-swizzled, B stride-5-granule (conflict-free); T14 dbuf.
// ---------------------------------------------------------------------------
__global__ __launch_bounds__(256) void k_fc1(const _Float16* __restrict__ Ah,
                                             const _Float16* __restrict__ Bp,
                                             const float* __restrict__ bias,
                                             _Float16* __restrict__ Hh) {
    __shared__ _Float16 Al[2][4096];
    __shared__ _Float16 Bl[2][2560];   // 64 oc x 5-granule stride (4 used)
    int tid = threadIdx.x;
    int i0 = blockIdx.x * 128, n0 = blockIdx.y * 64;
    int wid = tid >> 6, lane = tid & 63;
    int rr = lane & 15, kg = lane >> 4;

    int ca0 = tid, ca1 = tid + 256;
    int ra0_ = ca0 >> 2, qa0 = ca0 & 3, ra1_ = ca1 >> 2, qa1 = ca1 & 3;
    int aw0 = (ra0_ * 4 + (qa0 ^ ((ra0_ >> 1) & 3))) * 8;
    int aw1 = (ra1_ * 4 + (qa1 ^ ((ra1_ >> 1) & 3))) * 8;
    int bwB = ((tid >> 2) * 5 + (tid & 3)) * 8;

    uint4 xa0, xa1, xb0;
    auto loadT = [&](int t) {
        xa0 = *(const uint4*)(Ah + (size_t)(i0 + ra0_) * 800 + t * 32 + qa0 * 8);
        xa1 = *(const uint4*)(Ah + (size_t)(i0 + ra1_) * 800 + t * 32 + qa1 * 8);
        const uint4* g = (const uint4*)Bp + (size_t)t * 4096 + (size_t)n0 * 8;
        xb0 = g[(tid >> 2) * 8 + (tid & 3)];     // hi half of row n0+(tid>>2)
    };
    auto writeT = [&](int buf) {
        *(uint4*)(&Al[buf][aw0]) = xa0;
        *(uint4*)(&Al[buf][aw1]) = xa1;
        *(uint4*)(&Bl[buf][bwB]) = xb0;
    };

    int aoff[2], bhoff[4];
#pragma unroll
    for (int mf = 0; mf < 2; ++mf) {
        int r = wid * 32 + mf * 16 + rr;
        aoff[mf] = (r * 4 + (kg ^ ((rr >> 1) & 3))) * 8;
    }
#pragma unroll
    for (int nf = 0; nf < 4; ++nf)
        bhoff[nf] = ((nf * 16 + rr) * 5 + kg) * 8;

    v4f zero = {0.f, 0.f, 0.f, 0.f};
    v4f acc[2][4];
#pragma unroll
    for (int mf = 0; mf < 2; ++mf)
#pragma unroll
        for (int nf = 0; nf < 4; ++nf) acc[mf][nf] = zero;

    loadT(0);
    writeT(0);
    __syncthreads();

    for (int t = 0; t < 25; ++t) {
        int cur = t & 1;
        if (t < 24) loadT(t + 1);
        v8h af[2], bh[4];
#pragma unroll
        for (int mf = 0; mf < 2; ++mf) af[mf] = *(const v8h*)(&Al[cur][aoff[mf]]);
#pragma unroll
        for (int nf = 0; nf < 4; ++nf) bh[nf] = *(const v8h*)(&Bl[cur][bhoff[nf]]);
#pragma unroll
        for (int mf = 0; mf < 2; ++mf)
#pragma unroll
            for (int nf = 0; nf < 4; ++nf)
                acc[mf][nf] = __builtin_amdgcn_mfma_f32_16x16x32_f16(af[mf], bh[nf], acc[mf][nf], 0, 0, 0);
        if (t < 24) writeT(cur ^ 1);
        __syncthreads();
    }

#pragma unroll
    for (int mf = 0; mf < 2; ++mf)
#pragma unroll
        for (int nf = 0; nf < 4; ++nf) {
            int col = n0 + nf * 16 + rr;
            float bs = bias[col < 500 ? col : 0];
#pragma unroll
            for (int j = 0; j < 4; ++j) {
                int row = i0 + wid * 32 + mf * 16 + kg * 4 + j;
                float v = fmaxf(trunc13(acc[mf][nf][j] + bs), 0.f);
                if (col < 500) Hh[(size_t)row * 512 + col] = (_Float16)v;
            }
        }
}

// ---------------------------------------------------------------------------
// K4: fc2 (500->10) + bias + trunc + log_softmax.  One wave per row, fp16 H.
// ---------------------------------------------------------------------------
__global__ __launch_bounds__(256) void k_fc2(const _Float16* __restrict__ Hh,
                                             const float* __restrict__ W,
                                             const float* __restrict__ bias,
                                             float* __restrict__ out) {
    int wave = threadIdx.x >> 6;
    int lane = threadIdx.x & 63;
    int i = blockIdx.x * 4 + wave;
    const _Float16* hrow = Hh + (size_t)i * 512;

    float p[10];
#pragma unroll
    for (int j = 0; j < 10; ++j) p[j] = 0.f;
    for (int k = lane; k < 500; k += 64) {
        float h = (float)hrow[k];
#pragma unroll
        for (int j = 0; j < 10; ++j) p[j] += h * W[j * 500 + k];
    }
#pragma unroll
    for (int j = 0; j < 10; ++j)
#pragma unroll
        for (int off = 32; off; off >>= 1) p[j] += __shfl_xor(p[j], off, 64);

    if (lane == 0) {
        float z[10], m = -1e30f;
#pragma unroll
        for (int j = 0; j < 10; ++j) {
            z[j] = trunc13(p[j] + bias[j]);
            m = fmaxf(m, z[j]);
        }
        float s = 0.f;
#pragma unroll
        for (int j = 0; j < 10; ++j) s += expf(z[j] - m);
        float lse = m + logf(s);
#pragma unroll
        for (int j = 0; j < 10; ++j) out[(size_t)i * 10 + j] = z[j] - lse;
    }
}

// ---------------------------------------------------------------------------
extern "C" void kernel_launch(void* const* d_in, const int* in_sizes, int n_in,
                              void* d_out, int out_size, void* d_ws, size_t ws_size,
                              hipStream_t stream) {
    const float* x   = (const float*)d_in[0];
    const float* w1  = (const float*)d_in[1];
    const float* b1  = (const float*)d_in[2];
    const float* w2  = (const float*)d_in[3];
    const float* b2  = (const float*)d_in[4];
    const float* wf1 = (const float*)d_in[5];
    const float* bf1 = (const float*)d_in[6];
    const float* wf2 = (const float*)d_in[7];
    const float* bf2 = (const float*)d_in[8];
    float* out = (float*)d_out;

    char* ws = (char*)d_ws;
    _Float16* p1h  = (_Float16*)(ws);                   // 28,311,552
    _Float16* p2h  = (_Float16*)(ws + 28311552);        //  6,553,600
    _Float16* h1h  = (_Float16*)(ws + 34865152);        //  4,194,304
    _Float16* wph  = (_Float16*)(ws + 39059456);        //     81,920
    _Float16* wpf1 = (_Float16*)(ws + 39141376);        //  1,638,400

    k_wprep<<<5, 256, 0, stream>>>(w2, wph);
    k_w1prep<<<50, 256, 0, stream>>>(wf1, wpf1);
    k_conv1<<<2304, 256, 0, stream>>>(x, w1, b1, p1h);
    k_conv2<<<512, 256, 0, stream>>>(p1h, wph, b2, p2h);
    dim3 g3(32, 8);
    k_fc1<<<g3, 256, 0, stream>>>(p2h, wpf1, bf1, h1h);
    k_fc2<<<1024, 256, 0, stream>>>(h1h, wf2, bf2, out);
}

// Round 20
// 96.887 us; speedup vs baseline: 1.8888x; 1.2230x over previous
//
#include <hip/hip_runtime.h>

// LeNet forward, BATCH=4096. trunc = zero low 13 bits of fp32 mantissa.
// ALL layers via fp16 MFMA (hi-plane weights only; R17/R18 verified the
// rounding is sub-trunc-granule for conv2/fc1; conv1 adds ~1e-3 from fp16
// x -- predicted final absmax <= ~0.035 < 0.0503).
// conv1: M=pre-pool positions, N=20(2 tiles), K=25 taps pad 32 (ONE step);
// fragment = 4x4 pre-pool block; pool = j-pairs + shfl_xor(16) in-register.
// ws layout (bytes):
//   p1h  [4096][144][24] fp16 @ 0            (28,311,552)
//   p2h  [4096][800]     fp16 @ 28,311,552   ( 6,553,600)
//   h1h  [4096][512]     fp16 @ 34,865,152   ( 4,194,304)
//   wph  [20][64][32]    fp16 @ 39,059,456   (    81,920)
//   wpf1 [25][512][64]   fp16 @ 39,141,376   ( 1,638,400)
//   wpc1 [2][64][8]      fp16 @ 40,779,776   (     2,048)

typedef _Float16 v8h __attribute__((ext_vector_type(8)));
typedef float v4f __attribute__((ext_vector_type(4)));

__device__ __forceinline__ float trunc13(float v) {
    return __int_as_float(__float_as_int(v) & (int)0xFFFFE000u);
}

// ---------------------------------------------------------------------------
// K0: ALL weight prep in one kernel.
// ids [0,1280): conv2 hi plane wph[t][oc][s] (pix=k/24, icr=k%24)
// ids [1280,1408): conv1 B-frags wpc1[tile][lane][8]
// ids [1408,14208): fc1 wpf1[t][oc][0..32)=hi, [32..64)=lo (hi used)
// ---------------------------------------------------------------------------
__global__ void k_prep(const float* __restrict__ w1, const float* __restrict__ w2,
                       const float* __restrict__ wf1,
                       _Float16* __restrict__ wpc1, _Float16* __restrict__ wph,
                       _Float16* __restrict__ wpf1) {
    int id = blockIdx.x * 256 + threadIdx.x;
    if (id < 1280) {
        int t = id >> 6, oc = id & 63;
        _Float16* dh = wph + (size_t)id * 32;
        for (int s = 0; s < 32; ++s) {
            int k = t * 32 + s;
            int pix = (k * 2731) >> 16;       // /24, exact for k<640
            int icr = k - pix * 24;
            float w = 0.f;
            if (pix < 25 && icr < 20 && oc < 50)
                w = w2[oc * 500 + icr * 25 + pix];
            dh[s] = (_Float16)w;
        }
    } else if (id < 1408) {
        int l = id - 1280;
        int lane = l & 63, tile = l >> 6;
        int rr = lane & 15, kg = lane >> 4;
        int oc = tile * 16 + rr;
        _Float16* dst = wpc1 + (size_t)l * 8;
        for (int j = 0; j < 8; ++j) {
            int t = kg * 8 + j;
            float w = (oc < 20 && t < 25) ? w1[oc * 25 + t] : 0.f;
            dst[j] = (_Float16)w;
        }
    } else if (id < 14208) {
        int id2 = id - 1408;
        int t = id2 >> 9, oc = id2 & 511;
        _Float16* dst = wpf1 + (size_t)id2 * 64;
        for (int kk = 0; kk < 32; ++kk) {
            float w = (oc < 500) ? wf1[(size_t)oc * 800 + t * 32 + kk] : 0.f;
            _Float16 hi = (_Float16)w;
            dst[kk] = hi;
            dst[32 + kk] = (_Float16)(w - (float)hi);
        }
    }
}

// ---------------------------------------------------------------------------
// K1: conv1 via MFMA 16x16x32_f16 + fused bias/trunc/relu/pool.
// Block = 4 images, 4 waves (wave = image). 36 fragments (6x6 quad blocks);
// A built per-lane from 8 L1-hot global loads (+fp16 cvt); B in 2 regs.
// C row kg*4+j = position (py=kg,px=j); pool via j-pairs + shfl_xor(16).
// ---------------------------------------------------------------------------
__global__ __launch_bounds__(256) void k_conv1(const float* __restrict__ x,
                                               const _Float16* __restrict__ wpc1,
                                               const float* __restrict__ b1,
                                               _Float16* __restrict__ p1h) {
    int tid = threadIdx.x;
    int wid = tid >> 6, lane = tid & 63;
    int b = blockIdx.x * 4 + wid;
    int kg = lane >> 4, rr = lane & 15;
    int py = rr >> 2, px = rr & 3;

    v8h bf0 = *(const v8h*)(wpc1 + (size_t)lane * 8);
    v8h bf1 = *(const v8h*)(wpc1 + (size_t)(64 + lane) * 8);
    float bias0 = b1[rr];                         // oc = rr (0..15)
    float bias1 = (rr < 4) ? b1[16 + rr] : 0.f;   // oc = 16+rr

    // per-lane tap offsets (taps kg*8+j, clamped to 24 for OOB-safe addr)
    int off[8];
#pragma unroll
    for (int j = 0; j < 8; ++j) {
        int t = kg * 8 + j;
        if (t > 24) t = 24;                       // B=0 there; value irrelevant
        int ky = (t * 205) >> 10;                 // /5
        int kx = t - 5 * ky;
        off[j] = (py + ky) * 28 + (px + kx);
    }

    const float* img = x + (size_t)b * 784;
    _Float16* outb = p1h + (size_t)b * 144 * 24;

    for (int qy = 0; qy < 6; ++qy) {
#pragma unroll
        for (int qx = 0; qx < 6; ++qx) {
            const float* base = img + (qy * 4) * 28 + qx * 4;
            v8h a;
#pragma unroll
            for (int j = 0; j < 8; ++j) a[j] = (_Float16)base[off[j]];

            v4f acc0 = {0.f, 0.f, 0.f, 0.f}, acc1 = {0.f, 0.f, 0.f, 0.f};
            acc0 = __builtin_amdgcn_mfma_f32_16x16x32_f16(a, bf0, acc0, 0, 0, 0);
            acc1 = __builtin_amdgcn_mfma_f32_16x16x32_f16(a, bf1, acc1, 0, 0, 0);

            // tile0 (oc=rr)
            float z0 = fmaxf(trunc13(acc0[0] + bias0), 0.f);
            float z1 = fmaxf(trunc13(acc0[1] + bias0), 0.f);
            float z2 = fmaxf(trunc13(acc0[2] + bias0), 0.f);
            float z3 = fmaxf(trunc13(acc0[3] + bias0), 0.f);
            float m01 = fmaxf(z0, z1), m23 = fmaxf(z2, z3);
            float p01 = fmaxf(m01, __shfl_xor(m01, 16, 64));
            float p23 = fmaxf(m23, __shfl_xor(m23, 16, 64));
            // tile1 (oc=16+rr, valid rr<4)
            float y0 = fmaxf(trunc13(acc1[0] + bias1), 0.f);
            float y1 = fmaxf(trunc13(acc1[1] + bias1), 0.f);
            float y2 = fmaxf(trunc13(acc1[2] + bias1), 0.f);
            float y3 = fmaxf(trunc13(acc1[3] + bias1), 0.f);
            float n01 = fmaxf(y0, y1), n23 = fmaxf(y2, y3);
            float q01 = fmaxf(n01, __shfl_xor(n01, 16, 64));
            float q23 = fmaxf(n23, __shfl_xor(n23, 16, 64));

            if (!(kg & 1)) {
                int pos0 = (2 * qy + (kg >> 1)) * 12 + 2 * qx;
                _Float16* o = outb + (size_t)pos0 * 24;
                o[rr]      = (_Float16)p01;       // (row, 2qx)
                o[24 + rr] = (_Float16)p23;       // (row, 2qx+1)
                if (rr < 4) {
                    o[16 + rr]      = (_Float16)q01;
                    o[24 + 16 + rr] = (_Float16)q23;
                }
            }
        }
    }
}

// ---------------------------------------------------------------------------
// K2: conv2 via MFMA 16x16x32_f16, hi-only. Block = 8 images, 4 waves;
// wave = 2 images (my=8), nt=4; 2 K-steps/iter -> 64-MFMA bursts.
// ---------------------------------------------------------------------------
#define AIMG3 3744   // 156 rows * 24 halfs (rows 144..155 zero pad)
__global__ __launch_bounds__(256, 2) void k_conv2(const _Float16* __restrict__ p1h,
                                                  const _Float16* __restrict__ wph,
                                                  const float* __restrict__ b2,
                                                  _Float16* __restrict__ p2h) {
    __shared__ __align__(16) _Float16 Al[8 * AIMG3];   // 59904 B
    int tid = threadIdx.x;
    int b0 = blockIdx.x * 8;

    {
        const uint4* src = (const uint4*)(p1h + (size_t)b0 * 3456);
        uint4* dst = (uint4*)Al;
        uint4 z = make_uint4(0u, 0u, 0u, 0u);
        for (int i = tid; i < 3744; i += 256) {
            int img = i / 468, r = i - img * 468;
            dst[i] = (r < 432) ? src[img * 432 + r] : z;
        }
    }
    __syncthreads();

    int wid = tid >> 6, lane = tid & 63;
    int kg = lane >> 4, rr = lane & 15;
    int Y = rr >> 3, xx = rr & 7;
    const _Float16* Ab0 = Al + (wid * 2) * AIMG3;
    const _Float16* Ab1 = Ab0 + AIMG3;
    const _Float16* abase[8];
#pragma unroll
    for (int my = 0; my < 4; ++my) {
        abase[my]     = Ab0 + ((2 * my + Y) * 12 + xx) * 24;
        abase[my + 4] = Ab1 + ((2 * my + Y) * 12 + xx) * 24;
    }
    const _Float16* bh_base = wph + rr * 32 + kg * 8;

    v4f acc[8][4];
#pragma unroll
    for (int my = 0; my < 8; ++my)
#pragma unroll
        for (int nt = 0; nt < 4; ++nt) acc[my][nt] = (v4f){0.f, 0.f, 0.f, 0.f};

    for (int u = 0; u < 10; ++u) {
        int t0 = 2 * u, t1 = 2 * u + 1;
        v8h bA[4], bB[4];
#pragma unroll
        for (int nt = 0; nt < 4; ++nt) {
            bA[nt] = *(const v8h*)(bh_base + t0 * 2048 + nt * 512);
            bB[nt] = *(const v8h*)(bh_base + t1 * 2048 + nt * 512);
        }
        {
            int k0 = t0 * 32 + kg * 8;
            int pix = (k0 * 2731) >> 16;
            int icol = k0 - pix * 24;
            int ky = (pix * 205) >> 10;
            int kx = pix - 5 * ky;
            int aofs = (ky * 12 + kx) * 24 + icol;
            v8h af[8];
#pragma unroll
            for (int my = 0; my < 8; ++my)
                af[my] = *(const v8h*)(abase[my] + aofs);
#pragma unroll
            for (int my = 0; my < 8; ++my)
#pragma unroll
                for (int nt = 0; nt < 4; ++nt)
                    acc[my][nt] = __builtin_amdgcn_mfma_f32_16x16x32_f16(af[my], bA[nt], acc[my][nt], 0, 0, 0);
        }
        {
            int k0 = t1 * 32 + kg * 8;
            int pix = (k0 * 2731) >> 16;
            int icol = k0 - pix * 24;
            int ky = (pix * 205) >> 10;
            int kx = pix - 5 * ky;
            int aofs = (ky * 12 + kx) * 24 + icol;
            v8h af[8];
#pragma unroll
            for (int my = 0; my < 8; ++my)
                af[my] = *(const v8h*)(abase[my] + aofs);
#pragma unroll
            for (int my = 0; my < 8; ++my)
#pragma unroll
                for (int nt = 0; nt < 4; ++nt)
                    acc[my][nt] = __builtin_amdgcn_mfma_f32_16x16x32_f16(af[my], bB[nt], acc[my][nt], 0, 0, 0);
        }
    }

#pragma unroll
    for (int h = 0; h < 2; ++h) {
        int imgg = b0 + wid * 2 + h;
#pragma unroll
        for (int nt = 0; nt < 4; ++nt) {
            int oc = nt * 16 + rr;
            float bias = (oc < 50) ? b2[oc] : 0.f;
#pragma unroll
            for (int my = 0; my < 4; ++my) {
                v4f a = acc[h * 4 + my][nt];
                float z0 = fmaxf(trunc13(a[0] + bias), 0.f);
                float z1 = fmaxf(trunc13(a[1] + bias), 0.f);
                float z2 = fmaxf(trunc13(a[2] + bias), 0.f);
                float z3 = fmaxf(trunc13(a[3] + bias), 0.f);
                float s0 = fmaxf(z0, z1), s2 = fmaxf(z2, z3);
                float o0 = fmaxf(s0, __shfl_xor(s0, 32, 64));
                float o2 = fmaxf(s2, __shfl_xor(s2, 32, 64));
                if (kg < 2 && oc < 50) {
                    p2h[(size_t)imgg * 800 + oc * 16 + my * 4 + 2 * kg]     = (_Float16)o0;
                    p2h[(size_t)imgg * 800 + oc * 16 + my * 4 + 2 * kg + 1] = (_Float16)o2;
                }
            }
        }
    }
}

// ---------------------------------------------------------------------------
// K3: fc1 via MFMA 16x16x32_f16, hi-only. BM=128 BN=64 BK=32, grid 32x8,
// 4 waves; A XOR-swizzled, B stride-5-granule (conflict-free); T14 dbuf.
// ---------------------------------------------------------------------------
__global__ __launch_bounds__(256) void k_fc1(const _Float16* __restrict__ Ah,
                                             const _Float16* __restrict__ Bp,
                                             const float* __restrict__ bias,
                                             _Float16* __restrict__ Hh) {
    __shared__ _Float16 Al[2][4096];
    __shared__ _Float16 Bl[2][2560];
    int tid = threadIdx.x;
    int i0 = blockIdx.x * 128, n0 = blockIdx.y * 64;
    int wid = tid >> 6, lane = tid & 63;
    int rr = lane & 15, kg = lane >> 4;

    int ca0 = tid, ca1 = tid + 256;
    int ra0_ = ca0 >> 2, qa0 = ca0 & 3, ra1_ = ca1 >> 2, qa1 = ca1 & 3;
    int aw0 = (ra0_ * 4 + (qa0 ^ ((ra0_ >> 1) & 3))) * 8;
    int aw1 = (ra1_ * 4 + (qa1 ^ ((ra1_ >> 1) & 3))) * 8;
    int bwB = ((tid >> 2) * 5 + (tid & 3)) * 8;

    uint4 xa0, xa1, xb0;
    auto loadT = [&](int t) {
        xa0 = *(const uint4*)(Ah + (size_t)(i0 + ra0_) * 800 + t * 32 + qa0 * 8);
        xa1 = *(const uint4*)(Ah + (size_t)(i0 + ra1_) * 800 + t * 32 + qa1 * 8);
        const uint4* g = (const uint4*)Bp + (size_t)t * 4096 + (size_t)n0 * 8;
        xb0 = g[(tid >> 2) * 8 + (tid & 3)];
    };
    auto writeT = [&](int buf) {
        *(uint4*)(&Al[buf][aw0]) = xa0;
        *(uint4*)(&Al[buf][aw1]) = xa1;
        *(uint4*)(&Bl[buf][bwB]) = xb0;
    };

    int aoff[2], bhoff[4];
#pragma unroll
    for (int mf = 0; mf < 2; ++mf) {
        int r = wid * 32 + mf * 16 + rr;
        aoff[mf] = (r * 4 + (kg ^ ((rr >> 1) & 3))) * 8;
    }
#pragma unroll
    for (int nf = 0; nf < 4; ++nf)
        bhoff[nf] = ((nf * 16 + rr) * 5 + kg) * 8;

    v4f zero = {0.f, 0.f, 0.f, 0.f};
    v4f acc[2][4];
#pragma unroll
    for (int mf = 0; mf < 2; ++mf)
#pragma unroll
        for (int nf = 0; nf < 4; ++nf) acc[mf][nf] = zero;

    loadT(0);
    writeT(0);
    __syncthreads();

    for (int t = 0; t < 25; ++t) {
        int cur = t & 1;
        if (t < 24) loadT(t + 1);
        v8h af[2], bh[4];
#pragma unroll
        for (int mf = 0; mf < 2; ++mf) af[mf] = *(const v8h*)(&Al[cur][aoff[mf]]);
#pragma unroll
        for (int nf = 0; nf < 4; ++nf) bh[nf] = *(const v8h*)(&Bl[cur][bhoff[nf]]);
#pragma unroll
        for (int mf = 0; mf < 2; ++mf)
#pragma unroll
            for (int nf = 0; nf < 4; ++nf)
                acc[mf][nf] = __builtin_amdgcn_mfma_f32_16x16x32_f16(af[mf], bh[nf], acc[mf][nf], 0, 0, 0);
        if (t < 24) writeT(cur ^ 1);
        __syncthreads();
    }

#pragma unroll
    for (int mf = 0; mf < 2; ++mf)
#pragma unroll
        for (int nf = 0; nf < 4; ++nf) {
            int col = n0 + nf * 16 + rr;
            float bs = bias[col < 500 ? col : 0];
#pragma unroll
            for (int j = 0; j < 4; ++j) {
                int row = i0 + wid * 32 + mf * 16 + kg * 4 + j;
                float v = fmaxf(trunc13(acc[mf][nf][j] + bs), 0.f);
                if (col < 500) Hh[(size_t)row * 512 + col] = (_Float16)v;
            }
        }
}

// ---------------------------------------------------------------------------
// K4: fc2 (500->10) + bias + trunc + log_softmax.  One wave per row, fp16 H.
// ---------------------------------------------------------------------------
__global__ __launch_bounds__(256) void k_fc2(const _Float16* __restrict__ Hh,
                                             const float* __restrict__ W,
                                             const float* __restrict__ bias,
                                             float* __restrict__ out) {
    int wave = threadIdx.x >> 6;
    int lane = threadIdx.x & 63;
    int i = blockIdx.x * 4 + wave;
    const _Float16* hrow = Hh + (size_t)i * 512;

    float p[10];
#pragma unroll
    for (int j = 0; j < 10; ++j) p[j] = 0.f;
    for (int k = lane; k < 500; k += 64) {
        float h = (float)hrow[k];
#pragma unroll
        for (int j = 0; j < 10; ++j) p[j] += h * W[j * 500 + k];
    }
#pragma unroll
    for (int j = 0; j < 10; ++j)
#pragma unroll
        for (int off = 32; off; off >>= 1) p[j] += __shfl_xor(p[j], off, 64);

    if (lane == 0) {
        float z[10], m = -1e30f;
#pragma unroll
        for (int j = 0; j < 10; ++j) {
            z[j] = trunc13(p[j] + bias[j]);
            m = fmaxf(m, z[j]);
        }
        float s = 0.f;
#pragma unroll
        for (int j = 0; j < 10; ++j) s += expf(z[j] - m);
        float lse = m + logf(s);
#pragma unroll
        for (int j = 0; j < 10; ++j) out[(size_t)i * 10 + j] = z[j] - lse;
    }
}

// ---------------------------------------------------------------------------
extern "C" void kernel_launch(void* const* d_in, const int* in_sizes, int n_in,
                              void* d_out, int out_size, void* d_ws, size_t ws_size,
                              hipStream_t stream) {
    const float* x   = (const float*)d_in[0];
    const float* w1  = (const float*)d_in[1];
    const float* b1  = (const float*)d_in[2];
    const float* w2  = (const float*)d_in[3];
    const float* b2  = (const float*)d_in[4];
    const float* wf1 = (const float*)d_in[5];
    const float* bf1 = (const float*)d_in[6];
    const float* wf2 = (const float*)d_in[7];
    const float* bf2 = (const float*)d_in[8];
    float* out = (float*)d_out;

    char* ws = (char*)d_ws;
    _Float16* p1h  = (_Float16*)(ws);                   // 28,311,552
    _Float16* p2h  = (_Float16*)(ws + 28311552);        //  6,553,600
    _Float16* h1h  = (_Float16*)(ws + 34865152);        //  4,194,304
    _Float16* wph  = (_Float16*)(ws + 39059456);        //     81,920
    _Float16* wpf1 = (_Float16*)(ws + 39141376);        //  1,638,400
    _Float16* wpc1 = (_Float16*)(ws + 40779776);        //      2,048

    k_prep<<<56, 256, 0, stream>>>(w1, w2, wf1, wpc1, wph, wpf1);
    k_conv1<<<1024, 256, 0, stream>>>(x, wpc1, b1, p1h);
    k_conv2<<<512, 256, 0, stream>>>(p1h, wph, b2, p2h);
    dim3 g3(32, 8);
    k_fc1<<<g3, 256, 0, stream>>>(p2h, wpf1, bf1, h1h);
    k_fc2<<<1024, 256, 0, stream>>>(h1h, wf2, bf2, out);
}